// Round 3
// baseline (271.849 us; speedup 1.0000x reference)
//
#include <hip/hip_runtime.h>
#include <math.h>
#include <stdint.h>

// GCNAgg: out = relu( (mean_s x[s]) * (1/sqrt(17)) @ W^T + b )
// x: [16][50000][256] fp32, W: [256][256] fp32 (row o, col i), b: [256] fp32
// out: [50000][256] fp32
//
// R3 structure: stack-OUTER streaming (contiguous 64KB/block/step) + register
// accumulators; MFMA phase over LDS bf16 tile. Bet: DRAM burst locality.

#define NSTACK 16
#define NNODES 50000
#define DIM    256
#define TM     64            // nodes per block
#define THREADS 512          // 8 waves
#define LDSTRIDE 264         // ushorts per LDS row (256 + 8 pad)

typedef __attribute__((ext_vector_type(8))) short  short8v;   // 8 bf16 (MFMA A/B frag)
typedef __attribute__((ext_vector_type(4))) float  float4v;   // MFMA C/D frag

__device__ __forceinline__ unsigned short f2bf(float f) {
    unsigned int u = __float_as_uint(f);
    u += 0x7FFFu + ((u >> 16) & 1u);
    return (unsigned short)(u >> 16);
}

// Kernel 0: convert W fp32 -> bf16 row-major into workspace (65536 elems)
__global__ void wconv_kernel(const float* __restrict__ W, unsigned short* __restrict__ Wbf) {
    int i = (blockIdx.x * blockDim.x + threadIdx.x) * 4;
    float4v w = *(const float4v*)(W + i);
    unsigned int lo = (unsigned int)f2bf(w.x) | ((unsigned int)f2bf(w.y) << 16);
    unsigned int hi = (unsigned int)f2bf(w.z) | ((unsigned int)f2bf(w.w) << 16);
    *(uint2*)(Wbf + i) = make_uint2(lo, hi);
}

template <bool PACKED>
__launch_bounds__(THREADS, 4)   // 4 waves/EU -> 16 waves/CU = 2 blocks; VGPR cap 128
__global__ void gcn_fused(const float* __restrict__ x,
                          const float* __restrict__ W,
                          const unsigned short* __restrict__ Wbf,
                          const float* __restrict__ bias,
                          float* __restrict__ out,
                          float scale) {
    __shared__ unsigned short mlds[TM * LDSTRIDE];   // 33792 B

    const int t     = threadIdx.x;
    const int tile0 = blockIdx.x * TM;

    // ---------- Phase 1: stack-outer streaming reduce -> scaled bf16 into LDS ----
    // thread t: channels chg..chg+3, nodes tile0 + ng*8 + nsub (ng=0..7)
    {
        const int chg  = (t & 63) * 4;
        const int nsub = t >> 6;          // 0..7

        float4v acc[8];
        #pragma unroll
        for (int ng = 0; ng < 8; ++ng) acc[ng] = (float4v){0.f, 0.f, 0.f, 0.f};

        const size_t nodeoff = (size_t)(tile0 + nsub) * DIM + chg;
        #pragma unroll 1
        for (int s = 0; s < NSTACK; ++s) {
            const float* ps = x + (size_t)s * NNODES * DIM + nodeoff;
            #pragma unroll
            for (int ng = 0; ng < 8; ++ng) {
                if (tile0 + ng * 8 + nsub < NNODES) {
                    acc[ng] += *(const float4v*)(ps + ng * 8 * DIM);
                }
            }
        }

        #pragma unroll
        for (int ng = 0; ng < 8; ++ng) {
            float4v a = acc[ng] * scale;
            unsigned int lo = (unsigned int)f2bf(a.x) | ((unsigned int)f2bf(a.y) << 16);
            unsigned int hi = (unsigned int)f2bf(a.z) | ((unsigned int)f2bf(a.w) << 16);
            *(uint2*)&mlds[(ng * 8 + nsub) * LDSTRIDE + chg] = make_uint2(lo, hi);
        }
    }
    __syncthreads();

    // ---------- Phase 2: 8 waves = 4 row-blocks x 2 col-halves, 64 MFMA each ----
    const int w       = t >> 6;          // 0..7
    const int l       = t & 63;
    const int l15     = l & 15;
    const int l4      = l >> 4;
    const int rowsel  = w & 3;           // row block: rows rowsel*16..+16
    const int colbase = (w >> 2) * 128;  // col half

    float4v acc2[8];
    #pragma unroll
    for (int i = 0; i < 8; ++i) acc2[i] = (float4v){0.f, 0.f, 0.f, 0.f};

    #pragma unroll
    for (int kb = 0; kb < 8; ++kb) {
        // A frag: lane l holds A[l&15][kb*32 + (l>>4)*8 + j], j=0..7
        const unsigned short* ap = &mlds[(rowsel * 16 + l15) * LDSTRIDE + kb * 32 + l4 * 8];
        short8v afrag = *(const short8v*)ap;
        #pragma unroll
        for (int cb = 0; cb < 8; ++cb) {
            // B frag: lane l holds B[k][col] = W[colbase+cb*16+l15][k]
            short8v bfrag;
            if (PACKED) {
                bfrag = *(const short8v*)(Wbf + (size_t)(colbase + cb * 16 + l15) * DIM
                                              + kb * 32 + l4 * 8);
            } else {
                const float* wr = W + (size_t)(colbase + cb * 16 + l15) * DIM + kb * 32 + l4 * 8;
                float4v w0 = *(const float4v*)wr;
                float4v w1 = *(const float4v*)(wr + 4);
                bfrag[0] = (short)f2bf(w0.x); bfrag[1] = (short)f2bf(w0.y);
                bfrag[2] = (short)f2bf(w0.z); bfrag[3] = (short)f2bf(w0.w);
                bfrag[4] = (short)f2bf(w1.x); bfrag[5] = (short)f2bf(w1.y);
                bfrag[6] = (short)f2bf(w1.z); bfrag[7] = (short)f2bf(w1.w);
            }
            acc2[cb] = __builtin_amdgcn_mfma_f32_16x16x32_bf16(afrag, bfrag, acc2[cb], 0, 0, 0);
        }
    }

    // ---------- Epilogue: +bias, ReLU, store (D[row=(l>>4)*4+r][col=l&15]) ------
    #pragma unroll
    for (int cb = 0; cb < 8; ++cb) {
        const int col = colbase + cb * 16 + l15;
        const float bv = bias[col];
        #pragma unroll
        for (int r = 0; r < 4; ++r) {
            const int row = tile0 + rowsel * 16 + l4 * 4 + r;
            if (row < NNODES) {
                float v = acc2[cb][r] + bv;
                out[(size_t)row * DIM + col] = v > 0.f ? v : 0.f;
            }
        }
    }
}

extern "C" void kernel_launch(void* const* d_in, const int* in_sizes, int n_in,
                              void* d_out, int out_size, void* d_ws, size_t ws_size,
                              hipStream_t stream) {
    const float* x  = (const float*)d_in[0];
    const float* W  = (const float*)d_in[1];
    const float* b  = (const float*)d_in[2];
    float* out      = (float*)d_out;

    const float scale = (float)(1.0 / (16.0 * sqrt(17.0)));   // mean(1/16) * 1/sqrt(n+1)
    const int nblocks = (NNODES + TM - 1) / TM;               // 782

    const bool packed = ws_size >= (size_t)(DIM * DIM * sizeof(unsigned short));
    if (packed) {
        unsigned short* Wbf = (unsigned short*)d_ws;
        wconv_kernel<<<dim3((DIM * DIM / 4 + 255) / 256), dim3(256), 0, stream>>>(W, Wbf);
        gcn_fused<true><<<dim3(nblocks), dim3(THREADS), 0, stream>>>(x, W, Wbf, b, out, scale);
    } else {
        gcn_fused<false><<<dim3(nblocks), dim3(THREADS), 0, stream>>>(x, W, nullptr, b, out, scale);
    }
}

// Round 4
// 209.465 us; speedup vs baseline: 1.2978x; 1.2978x over previous
//
#include <hip/hip_runtime.h>
#include <math.h>
#include <stdint.h>

// GCNAgg: out = relu( (mean_s x[s]) * (1/sqrt(17)) @ W^T + b )
// x: [16][50000][256] fp32, W: [256][256] fp32 (row o, col i), b: [256] fp32
// out: [50000][256] fp32
//
// R4 = R2 structure (best, 231us) + ONE variable: nontemporal loads on the
// 819MB read-once x stream + nontemporal stores on out. Tests whether the
// cache-allocation path is what caps streaming reads at ~3.7 TB/s.

#define NSTACK 16
#define NNODES 50000
#define DIM    256
#define TM     64            // nodes per block
#define LDSTRIDE 264         // ushorts per LDS row (256 + 8 pad -> 528B stride)

typedef __attribute__((ext_vector_type(8))) short  short8v;   // 8 bf16 (MFMA A/B frag)
typedef __attribute__((ext_vector_type(4))) float  float4v;   // MFMA C/D frag

__device__ __forceinline__ unsigned short f2bf(float f) {
    unsigned int u = __float_as_uint(f);
    u += 0x7FFFu + ((u >> 16) & 1u);
    return (unsigned short)(u >> 16);
}

// Kernel 0: convert W fp32 -> bf16 row-major into workspace (65536 elems)
__global__ void wconv_kernel(const float* __restrict__ W, unsigned short* __restrict__ Wbf) {
    int i = (blockIdx.x * blockDim.x + threadIdx.x) * 4;
    float4v w = *(const float4v*)(W + i);
    unsigned int lo = (unsigned int)f2bf(w.x) | ((unsigned int)f2bf(w.y) << 16);
    unsigned int hi = (unsigned int)f2bf(w.z) | ((unsigned int)f2bf(w.w) << 16);
    *(uint2*)(Wbf + i) = make_uint2(lo, hi);
}

template <bool PACKED>
__launch_bounds__(256, 4)   // 4 waves/EU -> 4 blocks/CU (16 waves), VGPR cap 128
__global__ void gcn_fused(const float* __restrict__ x,
                          const float* __restrict__ W,
                          const unsigned short* __restrict__ Wbf,
                          const float* __restrict__ bias,
                          float* __restrict__ out,
                          float scale) {
    __shared__ unsigned short mlds[TM * LDSTRIDE];   // 33792 B -> 4 blocks/CU fits 160KB

    const int t     = threadIdx.x;
    const int tile0 = blockIdx.x * TM;

    // ---------- Phase 1: reduce 16 stacks -> scaled mean, bf16 into LDS ----------
    {
        const int chg  = (t & 63) * 4;   // channel start (float4 granule); wave covers one node row
        const int nsub = t >> 6;         // 0..3
        #pragma unroll 1                 // bound VGPR pressure: one 16-load batch in flight/thread
        for (int ng = 0; ng < 16; ++ng) {
            const int nl   = ng * 4 + nsub;      // local node 0..63
            const int node = tile0 + nl;
            float4v acc = (float4v){0.f, 0.f, 0.f, 0.f};
            if (node < NNODES) {
                const float* p = x + (size_t)node * DIM + chg;
                #pragma unroll
                for (int s = 0; s < NSTACK; ++s) {
                    float4v v = __builtin_nontemporal_load((const float4v*)(p + (size_t)s * NNODES * DIM));
                    acc += v;
                }
            }
            acc *= scale;
            unsigned int lo = (unsigned int)f2bf(acc.x) | ((unsigned int)f2bf(acc.y) << 16);
            unsigned int hi = (unsigned int)f2bf(acc.z) | ((unsigned int)f2bf(acc.w) << 16);
            *(uint2*)&mlds[nl * LDSTRIDE + chg] = make_uint2(lo, hi);
        }
    }
    __syncthreads();

    // ---------- Phase 2: per-wave 16x256 output tile via mfma_f32_16x16x32_bf16 ----------
    const int w   = t >> 6;     // wave 0..3 -> rows [w*16, w*16+16)
    const int l   = t & 63;
    const int l15 = l & 15;
    const int l4  = l >> 4;

    float4v acc[16];
    #pragma unroll
    for (int i = 0; i < 16; ++i) acc[i] = (float4v){0.f, 0.f, 0.f, 0.f};

    #pragma unroll
    for (int kb = 0; kb < 8; ++kb) {
        // A frag: lane l holds A[l&15][kb*32 + (l>>4)*8 + j], j=0..7
        const unsigned short* ap = &mlds[(w * 16 + l15) * LDSTRIDE + kb * 32 + l4 * 8];
        short8v afrag = *(const short8v*)ap;
        #pragma unroll
        for (int cb = 0; cb < 16; ++cb) {
            // B frag: lane l holds B[k][l&15] = W[cb*16 + (l&15)][k], k = kb*32 + (l>>4)*8 + j
            short8v bfrag;
            if (PACKED) {
                bfrag = *(const short8v*)(Wbf + (size_t)(cb * 16 + l15) * DIM + kb * 32 + l4 * 8);
            } else {
                const float* wr = W + (size_t)(cb * 16 + l15) * DIM + kb * 32 + l4 * 8;
                float4v w0 = *(const float4v*)wr;
                float4v w1 = *(const float4v*)(wr + 4);
                bfrag[0] = (short)f2bf(w0.x); bfrag[1] = (short)f2bf(w0.y);
                bfrag[2] = (short)f2bf(w0.z); bfrag[3] = (short)f2bf(w0.w);
                bfrag[4] = (short)f2bf(w1.x); bfrag[5] = (short)f2bf(w1.y);
                bfrag[6] = (short)f2bf(w1.z); bfrag[7] = (short)f2bf(w1.w);
            }
            acc[cb] = __builtin_amdgcn_mfma_f32_16x16x32_bf16(afrag, bfrag, acc[cb], 0, 0, 0);
        }
    }

    // ---------- Epilogue: +bias, ReLU, nontemporal store ------------------------
    #pragma unroll
    for (int cb = 0; cb < 16; ++cb) {
        const int col = cb * 16 + l15;
        const float bv = bias[col];
        #pragma unroll
        for (int r = 0; r < 4; ++r) {
            const int row = tile0 + w * 16 + l4 * 4 + r;
            if (row < NNODES) {
                float v = acc[cb][r] + bv;
                v = v > 0.f ? v : 0.f;
                __builtin_nontemporal_store(v, &out[(size_t)row * DIM + col]);
            }
        }
    }
}

extern "C" void kernel_launch(void* const* d_in, const int* in_sizes, int n_in,
                              void* d_out, int out_size, void* d_ws, size_t ws_size,
                              hipStream_t stream) {
    const float* x  = (const float*)d_in[0];
    const float* W  = (const float*)d_in[1];
    const float* b  = (const float*)d_in[2];
    float* out      = (float*)d_out;

    const float scale = (float)(1.0 / (16.0 * sqrt(17.0)));   // mean(1/16) * 1/sqrt(n+1)
    const int nblocks = (NNODES + TM - 1) / TM;               // 782

    const bool packed = ws_size >= (size_t)(DIM * DIM * sizeof(unsigned short));
    if (packed) {
        unsigned short* Wbf = (unsigned short*)d_ws;
        wconv_kernel<<<dim3((DIM * DIM / 4 + 255) / 256), dim3(256), 0, stream>>>(W, Wbf);
        gcn_fused<true><<<dim3(nblocks), dim3(256), 0, stream>>>(x, W, Wbf, b, out, scale);
    } else {
        gcn_fused<false><<<dim3(nblocks), dim3(256), 0, stream>>>(x, W, nullptr, b, out, scale);
    }
}